// Round 4
// baseline (630.874 us; speedup 1.0000x reference)
//
#include <hip/hip_runtime.h>

// ---------------------------------------------------------------------------
// MoE FFN: SEQ=8192, IN_DIM=1024, HID=2048, 8 experts, topk=2, gelu(tanh) gate
// R4: BK=32 double-buffered pipeline -> 3-4 blocks/CU (LDS 48/32 KB), BN=128
// restored, loop-invariant LDS read addresses (one kk-step per stage), grid
// n-fastest so all n-blocks of a tile share the X/act tile in L2, weights
// stream from L3 (64 MB, L3-resident). Swizzle reworked for 4-chunk rows.
// ---------------------------------------------------------------------------

#define SEQ 8192
#define IN_DIM 1024
#define HID 2048
#define NEXP 8
#define TOPK 2
#define NSLOT (SEQ * TOPK)

#define BM 128
#define BK 32
#define MAX_TILES 136

typedef unsigned short ushort_t;
typedef __bf16 bf16x8 __attribute__((ext_vector_type(8)));
typedef float f32x4 __attribute__((ext_vector_type(4)));

__device__ __forceinline__ ushort_t f2bf(float f) {
    union { float f; unsigned u; } v;
    v.f = f;
    unsigned r = v.u + 0x7FFFu + ((v.u >> 16) & 1u);
    return (ushort_t)(r >> 16);
}

__device__ __forceinline__ float gelu_tanh(float x) {
    float u = 0.7978845608028654f * x * (1.0f + 0.044715f * x * x);
    return x / (1.0f + __expf(-2.0f * u));
}

__device__ __forceinline__ void async16(const void* g, void* l) {
    __builtin_amdgcn_global_load_lds(
        (const __attribute__((address_space(1))) unsigned int*)g,
        (__attribute__((address_space(3))) unsigned int*)l, 16, 0, 0);
}

// pipeline barriers: wait for all-but-N outstanding vmem (the just-issued
// prefetch), then barrier. Never vmcnt(0) mid-loop.
__device__ __forceinline__ void wait6_barrier() {
    asm volatile("s_waitcnt vmcnt(6)\ns_barrier" ::: "memory");
}
__device__ __forceinline__ void wait4_barrier() {
    asm volatile("s_waitcnt vmcnt(4)\ns_barrier" ::: "memory");
}
__device__ __forceinline__ void wait0_barrier() {
    asm volatile("s_waitcnt vmcnt(0)\ns_barrier" ::: "memory");
}
__device__ __forceinline__ void lds_barrier() {
    asm volatile("s_waitcnt lgkmcnt(0)\ns_barrier" ::: "memory");
}

// ---------------------------------------------------------------------------
__global__ void cast_bf16_kernel(const float* __restrict__ in,
                                 ushort_t* __restrict__ out, int n) {
    int i = (blockIdx.x * blockDim.x + threadIdx.x) * 4;
    if (i >= n) return;
    float4 v = *(const float4*)(in + i);
    union { ushort_t u[4]; uint2 v; } o;
    o.u[0] = f2bf(v.x); o.u[1] = f2bf(v.y);
    o.u[2] = f2bf(v.z); o.u[3] = f2bf(v.w);
    *(uint2*)(out + i) = o.v;
}

// down_proj [8][2048][1024] fp32 -> [8][1024][2048] bf16
__global__ void transpose_cast_kernel(const float* __restrict__ in,
                                      ushort_t* __restrict__ out) {
    __shared__ float tile[32][33];
    int e = blockIdx.z;
    int d0 = blockIdx.x * 32, h0 = blockIdx.y * 32;
    int tx = threadIdx.x & 31, ty = threadIdx.x >> 5;
    const float* src = in + (size_t)e * HID * IN_DIM;
    for (int j = 0; j < 32; j += 8)
        tile[ty + j][tx] = src[(size_t)(h0 + ty + j) * IN_DIM + d0 + tx];
    __syncthreads();
    ushort_t* dst = out + (size_t)e * IN_DIM * HID;
    for (int j = 0; j < 32; j += 8)
        dst[(size_t)(d0 + ty + j) * HID + h0 + tx] = f2bf(tile[tx][ty + j]);
}

// ---------------------------------------------------------------------------
__global__ void route_kernel(const int* __restrict__ sel,
                             const float* __restrict__ wts,
                             int* __restrict__ meta,
                             int* __restrict__ stok,
                             int* __restrict__ sinv) {
    __shared__ int lc[256][NEXP];
    __shared__ int tot[NEXP];
    __shared__ int s_off[NEXP + 1];
    int t = threadIdx.x;
    int cnt[NEXP];
#pragma unroll
    for (int e = 0; e < NEXP; e++) cnt[e] = 0;
    int base = t * (NSLOT / 256);
    for (int i = 0; i < NSLOT / 256; i++) cnt[sel[base + i]]++;
#pragma unroll
    for (int e = 0; e < NEXP; e++) lc[t][e] = cnt[e];
    __syncthreads();
    if (t < NEXP) {
        int run = 0;
        for (int i = 0; i < 256; i++) { int v = lc[i][t]; lc[i][t] = run; run += v; }
        tot[t] = run;
    }
    __syncthreads();
    if (t == 0) {
        int o = 0;
        for (int e = 0; e < NEXP; e++) { s_off[e] = o; o += tot[e]; }
        s_off[NEXP] = o;
        for (int e = 0; e <= NEXP; e++) meta[e] = s_off[e];
        int nt = 0;
        for (int e = 0; e < NEXP; e++) {
            int c = s_off[e + 1] - s_off[e];
            int m = (c + BM - 1) / BM;
            for (int i = 0; i < m; i++) { meta[32 + 2 * nt] = e; meta[33 + 2 * nt] = i; nt++; }
        }
        meta[16] = nt;
    }
    __syncthreads();
    int cur[NEXP];
#pragma unroll
    for (int e = 0; e < NEXP; e++) cur[e] = s_off[e] + lc[t][e];
    for (int i = 0; i < NSLOT / 256; i++) {
        int slot = base + i;
        int e = sel[slot];
        int pos = cur[e]++;
        stok[pos] = slot >> 1;
        sinv[slot] = pos;
    }
}

// ---------------------------------------------------------------------------
// GEMM1: act = gelu(x@Wg^T) * (x@Wu^T). 128x128 tile, BK=32 dbuf (48 KB LDS,
// 3 blocks/CU). grid.x = n-block (16, fastest) -> X tile shared in L2.
__global__ __launch_bounds__(256) void gemm1_kernel(
    const ushort_t* __restrict__ X,
    const ushort_t* __restrict__ U,
    const ushort_t* __restrict__ G,
    const int* __restrict__ meta,
    const int* __restrict__ stok,
    ushort_t* __restrict__ act) {
    __shared__ __align__(16) ushort_t XT[2][BM * BK];   // 16 KB
    __shared__ __align__(16) ushort_t UT[2][BM * BK];   // 16 KB
    __shared__ __align__(16) ushort_t GT[2][BM * BK];   // 16 KB
    __shared__ int s_tok[BM];

    int tile = blockIdx.y;
    if (tile >= meta[16]) return;
    int e = meta[32 + 2 * tile];
    int mt = meta[33 + 2 * tile];
    int off = meta[e];
    int cnt = meta[e + 1] - off;
    int m0 = mt * BM;
    int n0 = blockIdx.x * 128;

    int tid = threadIdx.x;
    if (tid < BM) {
        int r = m0 + tid;
        if (r >= cnt) r = cnt - 1;
        s_tok[tid] = stok[off + r];
    }
    __syncthreads();

    int lane = tid & 63;
    int w = tid >> 6;
    int wr = w >> 1, wc = w & 1;
    // staging: 16 rows x 4 chunks (16 B) per wave-quarter; 2 iters cover 128 rows
    int srow = lane >> 2;                    // 0..15
    int schunk = lane & 3;                   // 0..3
    int gchunk = schunk ^ ((srow >> 1) & 3); // swizzled source chunk

    const ushort_t* Ue = U + ((size_t)e * HID + n0) * IN_DIM;
    const ushort_t* Ge = G + ((size_t)e * HID + n0) * IN_DIM;

    const ushort_t* xp[2];
    const ushort_t* up[2];
    const ushort_t* gp[2];
#pragma unroll
    for (int i = 0; i < 2; i++) {
        int r = w * 32 + i * 16 + srow;
        xp[i] = X + (size_t)s_tok[r] * IN_DIM + gchunk * 8;
        up[i] = Ue + (size_t)r * IN_DIM + gchunk * 8;
        gp[i] = Ge + (size_t)r * IN_DIM + gchunk * 8;
    }

    f32x4 accH[4][4], accG[4][4];
#pragma unroll
    for (int mi = 0; mi < 4; mi++)
#pragma unroll
        for (int ni = 0; ni < 4; ni++) {
            accH[mi][ni] = (f32x4){0.f, 0.f, 0.f, 0.f};
            accG[mi][ni] = (f32x4){0.f, 0.f, 0.f, 0.f};
        }

    int r4 = lane & 15;
    int q = lane >> 4;
    int cs = ((q ^ ((r4 >> 1) & 3)) << 3);   // loop-invariant swizzled k-offset
    int xoff[4], noff[4];
#pragma unroll
    for (int i = 0; i < 4; i++) {
        xoff[i] = (wr * 64 + i * 16 + r4) * BK + cs;
        noff[i] = (wc * 64 + i * 16 + r4) * BK + cs;
    }

#define G1_ISSUE(s)                                                        \
    {                                                                      \
        int _b = (s) & 1;                                                  \
        int _k0 = (s) * BK;                                                \
        _Pragma("unroll")                                                  \
        for (int i = 0; i < 2; i++) {                                      \
            int lo = (w * 32 + i * 16) * BK;                               \
            async16(xp[i] + _k0, &XT[_b][lo]);                             \
            async16(up[i] + _k0, &UT[_b][lo]);                             \
            async16(gp[i] + _k0, &GT[_b][lo]);                             \
        }                                                                  \
    }

#define G1_COMPUTE(s)                                                      \
    {                                                                      \
        int _b = (s) & 1;                                                  \
        bf16x8 a[4], bu[4], bg[4];                                         \
        _Pragma("unroll")                                                  \
        for (int i = 0; i < 4; i++) {                                      \
            a[i]  = *(const bf16x8*)&XT[_b][xoff[i]];                      \
            bu[i] = *(const bf16x8*)&UT[_b][noff[i]];                      \
            bg[i] = *(const bf16x8*)&GT[_b][noff[i]];                      \
        }                                                                  \
        _Pragma("unroll")                                                  \
        for (int mi = 0; mi < 4; mi++)                                     \
            _Pragma("unroll")                                              \
            for (int ni = 0; ni < 4; ni++) {                               \
                accH[mi][ni] = __builtin_amdgcn_mfma_f32_16x16x32_bf16(    \
                    a[mi], bu[ni], accH[mi][ni], 0, 0, 0);                 \
                accG[mi][ni] = __builtin_amdgcn_mfma_f32_16x16x32_bf16(    \
                    a[mi], bg[ni], accG[mi][ni], 0, 0, 0);                 \
            }                                                              \
    }

    const int NK = IN_DIM / BK;   // 32
    G1_ISSUE(0);
    for (int s = 0; s < NK - 1; s++) {
        G1_ISSUE(s + 1);          // 6 loads outstanding on top of stage s's 6
        wait6_barrier();          // stage s landed (each wave waits its own)
        G1_COMPUTE(s);
        lds_barrier();            // reads of buf s done before its reuse
    }
    wait0_barrier();
    G1_COMPUTE(NK - 1);

#pragma unroll
    for (int mi = 0; mi < 4; mi++) {
#pragma unroll
        for (int r = 0; r < 4; r++) {
            int row_local = wr * 64 + mi * 16 + q * 4 + r;
            int grow = m0 + row_local;
            if (grow >= cnt) continue;
            size_t orow = (size_t)(off + grow) * HID + n0 + wc * 64;
#pragma unroll
            for (int ni = 0; ni < 4; ni++) {
                float h = accH[mi][ni][r];
                float g = accG[mi][ni][r];
                act[orow + ni * 16 + r4] = f2bf(gelu_tanh(g) * h);
            }
        }
    }
}

// ---------------------------------------------------------------------------
// GEMM2: y[pos] = act[pos] @ Wd. 128x128 tile, BK=32 dbuf (32 KB LDS, 4
// blocks/CU). grid.x = n-block (8, fastest) -> act tile shared in L2.
__global__ __launch_bounds__(256) void gemm2_kernel(
    const ushort_t* __restrict__ act,
    const ushort_t* __restrict__ DT,
    const int* __restrict__ meta,
    float* __restrict__ y) {            // [NSLOT][IN_DIM] fp32
    __shared__ __align__(16) ushort_t AT[2][BM * BK];   // 16 KB
    __shared__ __align__(16) ushort_t BT[2][BM * BK];   // 16 KB

    int tile = blockIdx.y;
    if (tile >= meta[16]) return;
    int e = meta[32 + 2 * tile];
    int mt = meta[33 + 2 * tile];
    int off = meta[e];
    int cnt = meta[e + 1] - off;
    int m0 = mt * BM;
    int n0 = blockIdx.x * 128;

    int tid = threadIdx.x;
    int lane = tid & 63;
    int w = tid >> 6;
    int wr = w >> 1, wc = w & 1;
    int srow = lane >> 2;
    int schunk = lane & 3;
    int gchunk = schunk ^ ((srow >> 1) & 3);

    const ushort_t* Ae = act + (size_t)off * HID;
    const ushort_t* Be = DT + ((size_t)e * IN_DIM + n0) * HID;

    const ushort_t* ap[2];
    const ushort_t* bp[2];
#pragma unroll
    for (int i = 0; i < 2; i++) {
        int r = w * 32 + i * 16 + srow;
        int ar = m0 + r; if (ar >= cnt) ar = cnt - 1;
        ap[i] = Ae + (size_t)ar * HID + gchunk * 8;
        bp[i] = Be + (size_t)r * HID + gchunk * 8;
    }

    f32x4 acc[4][4];
#pragma unroll
    for (int mi = 0; mi < 4; mi++)
#pragma unroll
        for (int ni = 0; ni < 4; ni++) acc[mi][ni] = (f32x4){0.f, 0.f, 0.f, 0.f};

    int r4 = lane & 15;
    int q = lane >> 4;
    int cs = ((q ^ ((r4 >> 1) & 3)) << 3);
    int aoff[4], boff[4];
#pragma unroll
    for (int i = 0; i < 4; i++) {
        aoff[i] = (wr * 64 + i * 16 + r4) * BK + cs;
        boff[i] = (wc * 64 + i * 16 + r4) * BK + cs;
    }

#define G2_ISSUE(s)                                                        \
    {                                                                      \
        int _b = (s) & 1;                                                  \
        int _k0 = (s) * BK;                                                \
        _Pragma("unroll")                                                  \
        for (int i = 0; i < 2; i++) {                                      \
            int lo = (w * 32 + i * 16) * BK;                               \
            async16(ap[i] + _k0, &AT[_b][lo]);                             \
            async16(bp[i] + _k0, &BT[_b][lo]);                             \
        }                                                                  \
    }

#define G2_COMPUTE(s)                                                      \
    {                                                                      \
        int _b = (s) & 1;                                                  \
        bf16x8 a[4], b[4];                                                 \
        _Pragma("unroll")                                                  \
        for (int i = 0; i < 4; i++) {                                      \
            a[i] = *(const bf16x8*)&AT[_b][aoff[i]];                       \
            b[i] = *(const bf16x8*)&BT[_b][boff[i]];                       \
        }                                                                  \
        _Pragma("unroll")                                                  \
        for (int mi = 0; mi < 4; mi++)                                     \
            _Pragma("unroll")                                              \
            for (int ni = 0; ni < 4; ni++)                                 \
                acc[mi][ni] = __builtin_amdgcn_mfma_f32_16x16x32_bf16(     \
                    a[mi], b[ni], acc[mi][ni], 0, 0, 0);                   \
    }

    const int NK = HID / BK;   // 64
    G2_ISSUE(0);
    for (int s = 0; s < NK - 1; s++) {
        G2_ISSUE(s + 1);
        wait4_barrier();
        G2_COMPUTE(s);
        lds_barrier();
    }
    wait0_barrier();
    G2_COMPUTE(NK - 1);

#pragma unroll
    for (int mi = 0; mi < 4; mi++) {
#pragma unroll
        for (int r = 0; r < 4; r++) {
            int row_local = wr * 64 + mi * 16 + q * 4 + r;
            int grow = m0 + row_local;
            if (grow >= cnt) continue;
            float* orow = y + (size_t)(off + grow) * IN_DIM + n0 + wc * 64;
#pragma unroll
            for (int ni = 0; ni < 4; ni++)
                orow[ni * 16 + r4] = acc[mi][ni][r];
        }
    }
}

// ---------------------------------------------------------------------------
// combine: out[tok] = w0*y[sinv[2tok]] + w1*y[sinv[2tok+1]]
__global__ __launch_bounds__(256) void combine_kernel(
    const float* __restrict__ y,
    const float* __restrict__ wts,
    const int* __restrict__ sinv,
    float* __restrict__ out) {
    int tok = blockIdx.x;
    int c = threadIdx.x;
    int p0 = sinv[tok * 2], p1 = sinv[tok * 2 + 1];
    float w0 = wts[tok * 2], w1 = wts[tok * 2 + 1];
    float4 a = *(const float4*)(y + (size_t)p0 * IN_DIM + c * 4);
    float4 b = *(const float4*)(y + (size_t)p1 * IN_DIM + c * 4);
    float4 o;
    o.x = w0 * a.x + w1 * b.x;
    o.y = w0 * a.y + w1 * b.y;
    o.z = w0 * a.z + w1 * b.z;
    o.w = w0 * a.w + w1 * b.w;
    *(float4*)(out + (size_t)tok * IN_DIM + c * 4) = o;
}

// ---------------------------------------------------------------------------
extern "C" void kernel_launch(void* const* d_in, const int* in_sizes, int n_in,
                              void* d_out, int out_size, void* d_ws, size_t ws_size,
                              hipStream_t stream) {
    const float* inp  = (const float*)d_in[0];
    const float* wts  = (const float*)d_in[1];
    const float* up   = (const float*)d_in[2];
    const float* gate = (const float*)d_in[3];
    const float* down = (const float*)d_in[4];
    const int*   sel  = (const int*)d_in[5];
    float* out = (float*)d_out;

    // y (fp32, 64 MB) aliases inp_bf/up_bf/part of gate_bf — safe: gemm2
    // (writes y) is stream-ordered after gemm1 (last reader of those), and
    // the cast kernels rewrite them every call.
    char* ws = (char*)d_ws;
    ushort_t* inp_bf  = (ushort_t*)(ws);
    ushort_t* up_bf   = (ushort_t*)(ws + 16777216);
    ushort_t* gate_bf = (ushort_t*)(ws + 50331648);
    ushort_t* down_bf = (ushort_t*)(ws + 83886080);
    ushort_t* act     = (ushort_t*)(ws + 117440512);
    int*      stok    = (int*)(ws + 184549376);
    int*      sinv    = (int*)(ws + 184614912);
    int*      meta    = (int*)(ws + 184680448);
    float*    y       = (float*)(ws);

    cast_bf16_kernel<<<(SEQ * IN_DIM) / 1024, 256, 0, stream>>>(inp, inp_bf, SEQ * IN_DIM);
    cast_bf16_kernel<<<(NEXP * HID * IN_DIM) / 1024, 256, 0, stream>>>(up, up_bf, NEXP * HID * IN_DIM);
    cast_bf16_kernel<<<(NEXP * HID * IN_DIM) / 1024, 256, 0, stream>>>(gate, gate_bf, NEXP * HID * IN_DIM);
    transpose_cast_kernel<<<dim3(IN_DIM / 32, HID / 32, NEXP), 256, 0, stream>>>(down, down_bf);
    route_kernel<<<1, 256, 0, stream>>>(sel, wts, meta, stok, sinv);
    gemm1_kernel<<<dim3(HID / 128, MAX_TILES), 256, 0, stream>>>(inp_bf, up_bf, gate_bf, meta, stok, act);
    gemm2_kernel<<<dim3(IN_DIM / 128, MAX_TILES), 256, 0, stream>>>(act, down_bf, meta, y);
    combine_kernel<<<SEQ, 256, 0, stream>>>(y, wts, sinv, out);
}